// Round 3
// baseline (282.701 us; speedup 1.0000x reference)
//
#include <hip/hip_runtime.h>

typedef __attribute__((ext_vector_type(8))) short short8;
typedef __attribute__((ext_vector_type(4))) float f32x4;
typedef __attribute__((ext_vector_type(4))) int i32x4;

__device__ __forceinline__ unsigned short f2bf(float f) {
  unsigned u = __builtin_bit_cast(unsigned, f);
  u += 0x7fffu + ((u >> 16) & 1u);
  return (unsigned short)(u >> 16);
}

// ---------------- prep: Wt[1152][384] bf16 (transposed, fused QKV), bias[1152] ----------------
__global__ __launch_bounds__(256) void k_prepw(const float* __restrict__ Wq, const float* __restrict__ Wk,
                                               const float* __restrict__ Wv, const float* __restrict__ bq,
                                               const float* __restrict__ bk, const float* __restrict__ bv,
                                               unsigned short* __restrict__ Wt, float* __restrict__ bvec) {
  int i = blockIdx.x * 256 + threadIdx.x;   // 1152*384 = 442368 exact
  int n = i / 384, k = i - n * 384;
  int which = n / 384;                      // 0..2
  int c = n - which * 384;
  const float* W = (which == 0) ? Wq : (which == 1) ? Wk : Wv;
  Wt[i] = f2bf(W[k * 384 + c]);
  if (k == 0) {
    const float* bb = (which == 0) ? bq : (which == 1) ? bk : bv;
    bvec[n] = bb[c];
  }
}

// ---------------- prep: fused bias+mask table in MFMA lane layout ----------------
// T[w][h][jq][ik][lane][r]  (f32x4 per lane): value for q=jq*16+lr, k=ik*16+lg*4+r
__global__ __launch_bounds__(256) void k_prept(const float* __restrict__ tab, const int* __restrict__ ridx,
                                               const float* __restrict__ am, float* __restrict__ T) {
  int i = blockIdx.x * 256 + threadIdx.x;   // 196608 total = 768 blocks
  int lane = i & 63;
  int rest = i >> 6;                        // [wh][jq][ik] : 192*4*4
  int ik = rest & 3, jq = (rest >> 2) & 3, wh = rest >> 4;
  int h = wh % 12, w = wh / 12;
  int lr = lane & 15, lg = lane >> 4;
  int q = jq * 16 + lr;
  f32x4 v;
  #pragma unroll
  for (int r = 0; r < 4; ++r) {
    int k = ik * 16 + lg * 4 + r;
    v[r] = (q < 49 && k < 49) ? tab[ridx[q * 49 + k] * 12 + h] + am[w * 2401 + q * 49 + k] : 0.f;
  }
  *(f32x4*)(T + (size_t)i * 4) = v;
}

// ---------------- mega kernel: one block = one window (49 tokens), 12 waves = 12 heads ----------------
// LDS layout (dynamic, 153600 B):
//   phase 0/1: XL[64][384] bf16 swizzled at bytes 0..49151 (rows 49..63 zero)
//   phase 2+ (after barrier): per-wave region at pool + wid*6400 ushorts (12800 B):
//     Qs [49][40] at +0, Ks [49][40] at +1984, P (8 KB, overlays Qs+Ks), Vt [32][72] at +4096
__global__ __launch_bounds__(768, 3) void k_mega(const float* __restrict__ X,
                                                 const unsigned short* __restrict__ Wt,
                                                 const float* __restrict__ bvec,
                                                 const float* __restrict__ T,
                                                 float* __restrict__ out) {
  extern __shared__ unsigned short pool[];
  const int w = blockIdx.x;                 // window 0..1023
  const int tid = threadIdx.x;
  const int lane = tid & 63, wid = tid >> 6;  // wid = head 0..11
  const int lr = lane & 15, lg = lane >> 4;
  char* poolB = (char*)pool;

  // ---- phase 0: stage X window (fp32 -> bf16, swizzled, zero-padded rows 49..63) ----
  #pragma unroll
  for (int it = 0; it < 4; ++it) {
    int c = tid + 768 * it;                 // 3072 chunks of 8 elements
    int row = c / 48, c8 = c - row * 48;
    short8 v = {0, 0, 0, 0, 0, 0, 0, 0};
    if (row < 49) {
      const float* p = X + ((size_t)(w * 49 + row)) * 384 + c8 * 8;
      f32x4 f0 = *(const f32x4*)p;
      f32x4 f1 = *(const f32x4*)(p + 4);
      v[0] = (short)f2bf(f0[0]); v[1] = (short)f2bf(f0[1]); v[2] = (short)f2bf(f0[2]); v[3] = (short)f2bf(f0[3]);
      v[4] = (short)f2bf(f1[0]); v[5] = (short)f2bf(f1[1]); v[6] = (short)f2bf(f1[2]); v[7] = (short)f2bf(f1[3]);
    }
    *(short8*)(poolB + row * 768 + ((c8 * 16) ^ ((row & 7) << 4))) = v;
  }
  __syncthreads();

  // ---- phase 1: per-wave GEMM, 3 passes (Q,K,V), N=32 each, K=384 ----
  const unsigned swz = (unsigned)((lr & 7) << 4);
  unsigned hq[16], hk[16], hv[16];          // packed bf16 results (r0|r1<<16, r2|r3<<16)
  auto gemm_pass = [&](int p, float scl, unsigned* hd) {
    f32x4 acc[4][2] = {};
    const unsigned short* Bg = Wt + ((size_t)(p * 384 + wid * 32 + lr)) * 384;
    short8 aC[4], bC[2], aN[4], bN[2];
    #pragma unroll
    for (int mi = 0; mi < 4; ++mi)
      aC[mi] = *(const short8*)(poolB + (16 * mi + lr) * 768 + (unsigned)((0 + lg * 16) ^ swz));
    bC[0] = *(const short8*)(Bg + lg * 8);
    bC[1] = *(const short8*)(Bg + 16 * 384 + lg * 8);
    #pragma unroll 2
    for (int k = 0; k < 12; ++k) {
      if (k < 11) {
        #pragma unroll
        for (int mi = 0; mi < 4; ++mi)
          aN[mi] = *(const short8*)(poolB + (16 * mi + lr) * 768 + (unsigned)(((k + 1) * 64 + lg * 16) ^ swz));
        bN[0] = *(const short8*)(Bg + (k + 1) * 32 + lg * 8);
        bN[1] = *(const short8*)(Bg + 16 * 384 + (k + 1) * 32 + lg * 8);
      }
      #pragma unroll
      for (int mi = 0; mi < 4; ++mi)
        #pragma unroll
        for (int ni = 0; ni < 2; ++ni)
          acc[mi][ni] = __builtin_amdgcn_mfma_f32_16x16x32_bf16(aC[mi], bC[ni], acc[mi][ni], 0, 0, 0);
      #pragma unroll
      for (int mi = 0; mi < 4; ++mi) aC[mi] = aN[mi];
      bC[0] = bN[0]; bC[1] = bN[1];
    }
    float b0 = bvec[p * 384 + wid * 32 + lr];
    float b1 = bvec[p * 384 + wid * 32 + 16 + lr];
    #pragma unroll
    for (int mi = 0; mi < 4; ++mi)
      #pragma unroll
      for (int ni = 0; ni < 2; ++ni) {
        float bb = ni ? b1 : b0;
        float v0 = (acc[mi][ni][0] + bb) * scl;
        float v1 = (acc[mi][ni][1] + bb) * scl;
        float v2 = (acc[mi][ni][2] + bb) * scl;
        float v3 = (acc[mi][ni][3] + bb) * scl;
        hd[(mi * 2 + ni) * 2 + 0] = (unsigned)f2bf(v0) | ((unsigned)f2bf(v1) << 16);
        hd[(mi * 2 + ni) * 2 + 1] = (unsigned)f2bf(v2) | ((unsigned)f2bf(v3) << 16);
      }
  };
  gemm_pass(0, 0.17677669529663687f, hq);
  gemm_pass(1, 1.0f, hk);
  gemm_pass(2, 1.0f, hv);
  __syncthreads();   // all XL reads done before per-wave regions (which overlay XL) are written

  // ---- phase 2: per-wave staging of Q,K (row-major [49][40]) and V^T [32][72] ----
  unsigned short* reg = pool + wid * 6400;
  unsigned short* Qs = reg;
  unsigned short* Ks = reg + 1984;
  unsigned short* Vt = reg + 4096;
  char* Pb = (char*)reg;                     // P overlays Qs+Ks after they are consumed
  #pragma unroll
  for (int mi = 0; mi < 4; ++mi)
    #pragma unroll
    for (int ni = 0; ni < 2; ++ni)
      #pragma unroll
      for (int r = 0; r < 4; ++r) {
        int s = 16 * mi + 4 * lg + r;
        int d = ni * 16 + lr;
        unsigned short qv = (unsigned short)(hq[(mi * 2 + ni) * 2 + (r >> 1)] >> ((r & 1) * 16));
        unsigned short kv = (unsigned short)(hk[(mi * 2 + ni) * 2 + (r >> 1)] >> ((r & 1) * 16));
        unsigned short vv = (unsigned short)(hv[(mi * 2 + ni) * 2 + (r >> 1)] >> ((r & 1) * 16));
        if (s < 49) {
          Qs[s * 40 + d] = qv;
          Ks[s * 40 + d] = kv;
        }
        Vt[d * 72 + s] = vv;                 // all s (rows >=49 multiplied by P=0)
      }

  // ---- phase 3: attention for this wave's head ----
  short8 qf[4], kf[4];
  #pragma unroll
  for (int t = 0; t < 4; ++t) {
    int rq = t * 16 + lr; if (rq > 48) rq = 48;   // clamp; garbage rows/cols masked or discarded
    qf[t] = *(const short8*)&Qs[rq * 40 + lg * 8];
    kf[t] = *(const short8*)&Ks[rq * 40 + lg * 8];
  }
  f32x4 sc[4][4] = {};   // S^T[k][q] : [ik][jq]
  #pragma unroll
  for (int ik = 0; ik < 4; ++ik)
    #pragma unroll
    for (int jq = 0; jq < 4; ++jq)
      sc[ik][jq] = __builtin_amdgcn_mfma_f32_16x16x32_bf16(kf[ik], qf[jq], sc[ik][jq], 0, 0, 0);

  const float* Tb = T + ((size_t)((w & 15) * 12 + wid)) * 4096;
  #pragma unroll
  for (int jq = 0; jq < 4; ++jq) {
    #pragma unroll
    for (int ik = 0; ik < 4; ++ik) {
      f32x4 tv = *(const f32x4*)(Tb + ((jq * 4 + ik) * 64 + lane) * 4);
      #pragma unroll
      for (int r = 0; r < 4; ++r) {
        float v = sc[ik][jq][r] + tv[r];
        if (ik == 3) {                      // k = 48 + 4*lg + r : valid only lg==0,r==0
          if (r == 0) v = (lg == 0) ? v : -1e30f;
          else v = -1e30f;
        }
        sc[ik][jq][r] = v;
      }
    }
    float m = -1e30f;
    #pragma unroll
    for (int ik = 0; ik < 4; ++ik)
      #pragma unroll
      for (int r = 0; r < 4; ++r) m = fmaxf(m, sc[ik][jq][r]);
    m = fmaxf(m, __shfl_xor(m, 16));
    m = fmaxf(m, __shfl_xor(m, 32));
    float s = 0.f;
    #pragma unroll
    for (int ik = 0; ik < 4; ++ik)
      #pragma unroll
      for (int r = 0; r < 4; ++r) {
        float e = __expf(sc[ik][jq][r] - m);
        sc[ik][jq][r] = e;
        s += e;
      }
    s += __shfl_xor(s, 16);
    s += __shfl_xor(s, 32);
    float iv = 1.0f / s;
    int q = jq * 16 + lr;
    #pragma unroll
    for (int ik = 0; ik < 4; ++ik) {
      unsigned d0 = (unsigned)f2bf(sc[ik][jq][0] * iv) | ((unsigned)f2bf(sc[ik][jq][1] * iv) << 16);
      unsigned d1 = (unsigned)f2bf(sc[ik][jq][2] * iv) | ((unsigned)f2bf(sc[ik][jq][3] * iv) << 16);
      unsigned off = (unsigned)(q * 128 + ik * 32 + lg * 8) ^ ((unsigned)(lr & 7) << 4);
      *(uint2*)(Pb + off) = make_uint2(d0, d1);
    }
  }

  // PV : out[64][32] = P[64][64] @ V[64][32]
  short8 vf[2][2];
  #pragma unroll
  for (int kk = 0; kk < 2; ++kk)
    #pragma unroll
    for (int nl = 0; nl < 2; ++nl)
      vf[kk][nl] = *(const short8*)&Vt[(nl * 16 + lr) * 72 + kk * 32 + lg * 8];
  f32x4 ao[4][2] = {};
  #pragma unroll
  for (int i = 0; i < 4; ++i) {
    short8 pf[2];
    #pragma unroll
    for (int kk = 0; kk < 2; ++kk) {
      unsigned off = (unsigned)((i * 16 + lr) * 128 + (kk * 4 + lg) * 16) ^ ((unsigned)(lr & 7) << 4);
      pf[kk] = *(const short8*)(Pb + off);
    }
    #pragma unroll
    for (int nl = 0; nl < 2; ++nl)
      #pragma unroll
      for (int kk = 0; kk < 2; ++kk)
        ao[i][nl] = __builtin_amdgcn_mfma_f32_16x16x32_bf16(pf[kk], vf[kk][nl], ao[i][nl], 0, 0, 0);
  }

  // epilogue: out[w*49+q][wid*32+d] (P already normalized)
  #pragma unroll
  for (int i = 0; i < 4; ++i) {
    #pragma unroll
    for (int j2 = 0; j2 < 4; ++j2) {
      int q = i * 16 + lg * 4 + j2;
      if (q < 49) {
        #pragma unroll
        for (int nl = 0; nl < 2; ++nl) {
          int d = nl * 16 + lr;
          out[((size_t)(w * 49 + q)) * 384 + wid * 32 + d] = ao[i][nl][j2];
        }
      }
    }
  }
}

extern "C" void kernel_launch(void* const* d_in, const int* in_sizes, int n_in,
                              void* d_out, int out_size, void* d_ws, size_t ws_size,
                              hipStream_t stream) {
  const float* hs  = (const float*)d_in[0];
  const float* am  = (const float*)d_in[1];
  const float* Wq  = (const float*)d_in[2];
  const float* bq  = (const float*)d_in[3];
  const float* Wk  = (const float*)d_in[4];
  const float* bk  = (const float*)d_in[5];
  const float* Wv  = (const float*)d_in[6];
  const float* bv  = (const float*)d_in[7];
  const float* tab = (const float*)d_in[8];
  const int*   rix = (const int*)d_in[9];
  float* out = (float*)d_out;
  char* ws = (char*)d_ws;

  size_t o = 0;
  auto alloc = [&](size_t bytes) { size_t r = o; o = (o + bytes + 255) & ~(size_t)255; return r; };
  unsigned short* Wt   = (unsigned short*)(ws + alloc(1152ull * 384 * 2));
  float*          bvec = (float*)(ws + alloc(1152ull * 4));
  float*          Tt   = (float*)(ws + alloc(192ull * 4096 * 4));
  (void)ws_size; (void)in_sizes; (void)n_in; (void)out_size;

  static int lds_set = 0;
  (void)lds_set;
  hipFuncSetAttribute((const void*)k_mega, hipFuncAttributeMaxDynamicSharedMemorySize, 153600);

  k_prepw<<<1728, 256, 0, stream>>>(Wq, Wk, Wv, bq, bk, bv, Wt, bvec);
  k_prept<<<768, 256, 0, stream>>>(tab, rix, am, Tt);
  k_mega<<<1024, 768, 153600, stream>>>(hs, Wt, bvec, Tt, out);
}